// Round 15
// baseline (270.715 us; speedup 1.0000x reference)
//
#include <hip/hip_runtime.h>
#include <hip/hip_bf16.h>
#include <math.h>

#define NN 100000
#define NE 1000000
#define NPB 512                          // nodes per bucket (pow2, shift 9)
#define NBUC ((NN + NPB - 1) / NPB)      // 196
#define CAPB 8192                        // max staged edges per bucket
#define P1B 512                          // part1 blocks
#define P1E ((NE + P1B - 1) / P1B)       // 1954 edges per part1 block
#define BCAP 512                         // max edges per 8-node agg block

typedef __attribute__((ext_vector_type(8))) short bf16x8;
typedef __attribute__((ext_vector_type(4))) float f32x4;
typedef unsigned int u32;
typedef unsigned short u16;
typedef unsigned long long u64;

__device__ __forceinline__ u16 f2b(float f) {
    __hip_bfloat16 h = __float2bfloat16(f);
    return *reinterpret_cast<u16*>(&h);
}
__device__ __forceinline__ float b2f(u16 u) {
    __hip_bfloat16 h = *reinterpret_cast<__hip_bfloat16*>(&u);
    return __bfloat162float(h);
}
__device__ __forceinline__ float bflo(u32 v) { return __uint_as_float(v << 16); }
__device__ __forceinline__ float bfhi(u32 v) { return __uint_as_float(v & 0xffff0000u); }

// ============================== CSR: bucket count + scan ==============================

__global__ void bucket_cnt(const int* __restrict__ dst, int* __restrict__ bcnt, int E) {
    __shared__ int c[NBUC];
    for (int i = threadIdx.x; i < NBUC; i += 256) c[i] = 0;
    __syncthreads();
    int i = blockIdx.x * 256 + threadIdx.x;
    const int stride = gridDim.x * 256;
    for (; i < E; i += stride) atomicAdd(&c[dst[i] >> 9], 1);
    __syncthreads();
    for (int j = threadIdx.x; j < NBUC; j += 256)
        if (c[j]) atomicAdd(&bcnt[j], c[j]);
}

__global__ void bucket_scan(const int* __restrict__ bcnt, int* __restrict__ bbase,
                            int* __restrict__ gcur) {
    __shared__ int s[256];
    const int tid = threadIdx.x;
    int v = (tid < NBUC) ? bcnt[tid] : 0;
    s[tid] = v;
    __syncthreads();
    for (int off = 1; off < 256; off <<= 1) {
        int t = (tid >= off) ? s[tid - off] : 0;
        __syncthreads();
        s[tid] += t;
        __syncthreads();
    }
    if (tid < NBUC) {
        int excl = s[tid] - v;
        bbase[tid] = excl;
        gcur[tid] = excl;
    }
    if (tid == NBUC - 1) bbase[NBUC] = s[tid];
}

// ============================== CSR: bucketed edge partition ==============================

__global__ __launch_bounds__(256) void part1(const int* __restrict__ src,
                                             const int* __restrict__ dst,
                                             int* __restrict__ gcur,
                                             long long* __restrict__ ebuf) {
    __shared__ int cnt[256], sex[256], base[256], cur2[256], scn[256];
    __shared__ long long stage[P1E];
    const int tid = threadIdx.x;
    const int e0 = blockIdx.x * P1E;
    const int e1 = min(e0 + P1E, NE);
    cnt[tid] = 0;
    __syncthreads();
    for (int i = e0 + tid; i < e1; i += 256)
        atomicAdd(&cnt[dst[i] >> 9], 1);
    __syncthreads();
    int v = cnt[tid];
    scn[tid] = v;
    __syncthreads();
    #pragma unroll
    for (int off = 1; off < 256; off <<= 1) {
        int t = (tid >= off) ? scn[tid - off] : 0;
        __syncthreads();
        scn[tid] += t;
        __syncthreads();
    }
    sex[tid] = scn[tid] - v;
    if (tid < NBUC) base[tid] = (v > 0) ? atomicAdd(&gcur[tid], v) : 0;
    cur2[tid] = 0;
    __syncthreads();
    for (int i = e0 + tid; i < e1; i += 256) {
        int d = dst[i], s = src[i];
        int b = d >> 9;
        int slot = sex[b] + atomicAdd(&cur2[b], 1);
        stage[slot] = ((long long)(u32)d << 32) | (u32)s;
    }
    __syncthreads();
    const int tot = e1 - e0;
    for (int i = tid; i < tot; i += 256) {
        long long ll = stage[i];
        int b = (int)((u64)ll >> 32) >> 9;
        ebuf[(size_t)base[b] + (i - sex[b])] = ll;
    }
}

// per bucket: count per node, scan -> rowptr, scatter -> csrc (coalesced)
__global__ __launch_bounds__(256) void part2B(const int* __restrict__ bbase,
                                              const long long* __restrict__ ebuf,
                                              int* __restrict__ rowptr,
                                              int* __restrict__ csrc) {
    __shared__ int nb[NPB], cnt[NPB];
    __shared__ int stage[CAPB];
    __shared__ int ssum[256];
    const int tid = threadIdx.x;
    const int n0 = blockIdx.x << 9;
    const int nn = min(NPB, NN - n0);
    const int estart = bbase[blockIdx.x];
    const int eend = bbase[blockIdx.x + 1];
    const int tot = eend - estart;
    for (int i = tid; i < NPB; i += 256) cnt[i] = 0;
    __syncthreads();
    for (int i = estart + tid; i < eend; i += 256) {
        int ln = (int)((u64)ebuf[i] >> 32) - n0;
        atomicAdd(&cnt[ln], 1);
    }
    __syncthreads();
    int a = cnt[2 * tid], b = cnt[2 * tid + 1];
    int ts = a + b;
    ssum[tid] = ts;
    __syncthreads();
    #pragma unroll
    for (int off = 1; off < 256; off <<= 1) {
        int t = (tid >= off) ? ssum[tid - off] : 0;
        __syncthreads();
        ssum[tid] += t;
        __syncthreads();
    }
    int eb = ssum[tid] - ts;
    nb[2 * tid] = eb;
    nb[2 * tid + 1] = eb + a;
    if (2 * tid < nn)     rowptr[n0 + 2 * tid]     = estart + eb;
    if (2 * tid + 1 < nn) rowptr[n0 + 2 * tid + 1] = estart + eb + a;
    if (tid == 0 && blockIdx.x == gridDim.x - 1) rowptr[NN] = eend;
    __syncthreads();
    for (int i = tid; i < NPB; i += 256) cnt[i] = 0;
    __syncthreads();
    if (tot <= CAPB) {
        for (int i = estart + tid; i < eend; i += 256) {
            long long ll = ebuf[i];
            int ln = (int)((u64)ll >> 32) - n0;
            int pos = nb[ln] + atomicAdd(&cnt[ln], 1);
            stage[pos] = (int)ll;
        }
        __syncthreads();
        for (int i = tid; i < tot; i += 256) csrc[estart + i] = stage[i];
    } else {
        for (int i = estart + tid; i < eend; i += 256) {
            long long ll = ebuf[i];
            int ln = (int)((u64)ll >> 32) - n0;
            int pos = nb[ln] + atomicAdd(&cnt[ln], 1);
            csrc[estart + pos] = (int)ll;
        }
    }
}

// ============================== weight prep (fused 3 layers) ==============================

__global__ void transW3(const float* __restrict__ W1, u16* __restrict__ W1t,
                        const float* __restrict__ W2, u16* __restrict__ W2t,
                        const float* __restrict__ W3, u16* __restrict__ W3t) {
    int idx = blockIdx.x * 256 + threadIdx.x;
    if (idx < 32768) {
        int n = idx / 256, k = idx % 256;
        W1t[idx] = f2b(W1[(size_t)k * 128 + n]);
    } else if (idx < 32768 + 16384) {
        int j = idx - 32768;
        int n = j / 128, k = j % 128;
        W2t[j] = f2b(W2[(size_t)k * 128 + n]);
    } else if (idx < 32768 + 16384 + 6144) {
        int j = idx - 32768 - 16384;
        int n = j / 128, k = j % 128;
        W3t[j] = f2b((n < 40) ? W3[(size_t)k * 40 + n] : 0.f);
    }
}

// ============================== MFMA GEMM v7: A-loads issued BEFORE B staging ==============================
// Per K-chunk: (1) issue A loads into regs, (2) stage B into LDS, (3) barrier
// (drains A loads for free under staging), (4) convert (fp32 path) + MFMA.
template<int K, int NT, int OUTW, bool AF32, int NH>
__global__ __launch_bounds__(256, 2) void gemm_s(const void* __restrict__ Ap_,
                                                 const u16* __restrict__ Wt,
                                                 const float* __restrict__ al,
                                                 const float* __restrict__ ar,
                                                 u16* __restrict__ C,
                                                 float* __restrict__ el,
                                                 float* __restrict__ er, int M) {
    constexpr int KC = 128;
    constexpr int NKC = K / KC;
    constexpr int NB = NT * 16;
    constexpr int CHK = KC / 8;
    __shared__ u16 lB[NB * KC];
    const int tid = threadIdx.x;
    const int w = tid >> 6, l = tid & 63;
    const int lr = l & 15, lq = l >> 4;
    const int row0 = blockIdx.x * 64 + w * 16;
    const u16* Ab = (const u16*)Ap_;
    const float* Af = (const float*)Ap_;

    int gr0 = row0 + lr; if (gr0 >= M) gr0 = M - 1;
    const size_t aoff = (size_t)gr0 * K;

    f32x4 acc[NT] = {};
    #pragma unroll
    for (int kc = 0; kc < NKC; ++kc) {
        // ---- (1) issue A loads FIRST (complete under staging + barrier) ----
        float4 v0, v1, v2, v3, v4, v5, v6, v7;
        bf16x8 a0, a1, a2, a3;
        if (AF32) {
            const float* ap = &Af[aoff + kc * KC];
            v0 = *reinterpret_cast<const float4*>(ap + 0 * 32 + lq * 8);
            v1 = *reinterpret_cast<const float4*>(ap + 0 * 32 + lq * 8 + 4);
            v2 = *reinterpret_cast<const float4*>(ap + 1 * 32 + lq * 8);
            v3 = *reinterpret_cast<const float4*>(ap + 1 * 32 + lq * 8 + 4);
            v4 = *reinterpret_cast<const float4*>(ap + 2 * 32 + lq * 8);
            v5 = *reinterpret_cast<const float4*>(ap + 2 * 32 + lq * 8 + 4);
            v6 = *reinterpret_cast<const float4*>(ap + 3 * 32 + lq * 8);
            v7 = *reinterpret_cast<const float4*>(ap + 3 * 32 + lq * 8 + 4);
        } else {
            a0 = *reinterpret_cast<const bf16x8*>(&Ab[aoff + kc * KC + 0 * 32 + lq * 8]);
            a1 = *reinterpret_cast<const bf16x8*>(&Ab[aoff + kc * KC + 1 * 32 + lq * 8]);
            a2 = *reinterpret_cast<const bf16x8*>(&Ab[aoff + kc * KC + 2 * 32 + lq * 8]);
            a3 = *reinterpret_cast<const bf16x8*>(&Ab[aoff + kc * KC + 3 * 32 + lq * 8]);
        }
        // ---- (2) stage B chunk ----
        for (int idx = tid; idx < NB * CHK; idx += 256) {
            int row = idx / CHK, c = idx % CHK;
            float4 v = *reinterpret_cast<const float4*>(&Wt[(size_t)row * K + kc * KC + c * 8]);
            int cs = c ^ (row & 7);
            *reinterpret_cast<float4*>(&lB[row * KC + cs * 8]) = v;
        }
        __syncthreads();
        // ---- (3) convert (fp32 path) ----
        if (AF32) {
            a0[0] = (short)f2b(v0.x); a0[1] = (short)f2b(v0.y); a0[2] = (short)f2b(v0.z); a0[3] = (short)f2b(v0.w);
            a0[4] = (short)f2b(v1.x); a0[5] = (short)f2b(v1.y); a0[6] = (short)f2b(v1.z); a0[7] = (short)f2b(v1.w);
            a1[0] = (short)f2b(v2.x); a1[1] = (short)f2b(v2.y); a1[2] = (short)f2b(v2.z); a1[3] = (short)f2b(v2.w);
            a1[4] = (short)f2b(v3.x); a1[5] = (short)f2b(v3.y); a1[6] = (short)f2b(v3.z); a1[7] = (short)f2b(v3.w);
            a2[0] = (short)f2b(v4.x); a2[1] = (short)f2b(v4.y); a2[2] = (short)f2b(v4.z); a2[3] = (short)f2b(v4.w);
            a2[4] = (short)f2b(v5.x); a2[5] = (short)f2b(v5.y); a2[6] = (short)f2b(v5.z); a2[7] = (short)f2b(v5.w);
            a3[0] = (short)f2b(v6.x); a3[1] = (short)f2b(v6.y); a3[2] = (short)f2b(v6.z); a3[3] = (short)f2b(v6.w);
            a3[4] = (short)f2b(v7.x); a3[5] = (short)f2b(v7.y); a3[6] = (short)f2b(v7.z); a3[7] = (short)f2b(v7.w);
        }
        // ---- (4) MFMA k-steps ----
        #pragma unroll
        for (int ks = 0; ks < 4; ++ks) {
            bf16x8 aF = (ks == 0) ? a0 : (ks == 1) ? a1 : (ks == 2) ? a2 : a3;
            const int cs = (ks * 4 + lq) ^ (lr & 7);
            #pragma unroll
            for (int nr = 0; nr < NT; ++nr) {
                bf16x8 bF = *reinterpret_cast<const bf16x8*>(&lB[(nr * 16 + lr) * KC + cs * 8]);
                acc[nr] = __builtin_amdgcn_mfma_f32_16x16x32_bf16(aF, bF, acc[nr], 0, 0, 0);
            }
        }
        if (kc + 1 < NKC) __syncthreads();
    }

    float alv[NT], arv[NT];
    #pragma unroll
    for (int nr = 0; nr < NT; ++nr) {
        int c = nr * 16 + lr;
        alv[nr] = (c < OUTW) ? al[c] : 0.f;
        arv[nr] = (c < OUTW) ? ar[c] : 0.f;
    }
    #pragma unroll
    for (int reg = 0; reg < 4; ++reg) {
        int gr = row0 + lq * 4 + reg;
        bool ok = gr < M;
        if (ok) {
            #pragma unroll
            for (int nr = 0; nr < NT; ++nr) {
                int gc = nr * 16 + lr;
                if (gc < OUTW) C[(size_t)gr * OUTW + gc] = f2b(acc[nr][reg]);
            }
        }
        float pl[NH] = {}, pr[NH] = {};
        #pragma unroll
        for (int nr = 0; nr < NT; ++nr) {
            int hidx = (NH == 1) ? 0 : (nr >> 1);
            pl[hidx] = fmaf(acc[nr][reg], alv[nr], pl[hidx]);
            pr[hidx] = fmaf(acc[nr][reg], arv[nr], pr[hidx]);
        }
        #pragma unroll
        for (int o = 8; o >= 1; o >>= 1) {
            #pragma unroll
            for (int hh = 0; hh < NH; ++hh) {
                pl[hh] += __shfl_xor(pl[hh], o);
                pr[hh] += __shfl_xor(pr[hh], o);
            }
        }
        if (ok && lr == 0) {
            #pragma unroll
            for (int hh = 0; hh < NH; ++hh) {
                el[gr * NH + hh] = pl[hh];
                er[gr * NH + hh] = pr[hh];
            }
        }
    }
}

// ============================== MFMA GEMM v6b: 2 M-tiles/block, A-loads first ==============================
template<int K, int NT, int OUTW, int NH>
__global__ __launch_bounds__(256, 2) void gemm_s2(const u16* __restrict__ Ab,
                                                  const u16* __restrict__ Wt,
                                                  const float* __restrict__ al,
                                                  const float* __restrict__ ar,
                                                  u16* __restrict__ C,
                                                  float* __restrict__ el,
                                                  float* __restrict__ er, int M) {
    constexpr int KC = 128;
    constexpr int NKC = K / KC;
    constexpr int NB = NT * 16;
    constexpr int CHK = KC / 8;
    __shared__ u16 lB[NB * KC];
    const int tid = threadIdx.x;
    const int w = tid >> 6, l = tid & 63;
    const int lr = l & 15, lq = l >> 4;
    const int row0 = blockIdx.x * 128 + w * 16;
    const int row1 = row0 + 64;

    int gr0 = row0 + lr; if (gr0 >= M) gr0 = M - 1;
    int gr1 = row1 + lr; if (gr1 >= M) gr1 = M - 1;
    const size_t aoff0 = (size_t)gr0 * K;
    const size_t aoff1 = (size_t)gr1 * K;

    f32x4 acc[2][NT] = {};
    #pragma unroll
    for (int kc = 0; kc < NKC; ++kc) {
        // (1) issue 8 A loads first
        bf16x8 aA0 = *reinterpret_cast<const bf16x8*>(&Ab[aoff0 + kc * KC + 0 * 32 + lq * 8]);
        bf16x8 aA1 = *reinterpret_cast<const bf16x8*>(&Ab[aoff0 + kc * KC + 1 * 32 + lq * 8]);
        bf16x8 aA2 = *reinterpret_cast<const bf16x8*>(&Ab[aoff0 + kc * KC + 2 * 32 + lq * 8]);
        bf16x8 aA3 = *reinterpret_cast<const bf16x8*>(&Ab[aoff0 + kc * KC + 3 * 32 + lq * 8]);
        bf16x8 aB0 = *reinterpret_cast<const bf16x8*>(&Ab[aoff1 + kc * KC + 0 * 32 + lq * 8]);
        bf16x8 aB1 = *reinterpret_cast<const bf16x8*>(&Ab[aoff1 + kc * KC + 1 * 32 + lq * 8]);
        bf16x8 aB2 = *reinterpret_cast<const bf16x8*>(&Ab[aoff1 + kc * KC + 2 * 32 + lq * 8]);
        bf16x8 aB3 = *reinterpret_cast<const bf16x8*>(&Ab[aoff1 + kc * KC + 3 * 32 + lq * 8]);
        // (2) stage B
        for (int idx = tid; idx < NB * CHK; idx += 256) {
            int row = idx / CHK, c = idx % CHK;
            float4 v = *reinterpret_cast<const float4*>(&Wt[(size_t)row * K + kc * KC + c * 8]);
            int cs = c ^ (row & 7);
            *reinterpret_cast<float4*>(&lB[row * KC + cs * 8]) = v;
        }
        __syncthreads();
        // (3) MFMA
        #pragma unroll
        for (int ks = 0; ks < 4; ++ks) {
            bf16x8 aF0 = (ks == 0) ? aA0 : (ks == 1) ? aA1 : (ks == 2) ? aA2 : aA3;
            bf16x8 aF1 = (ks == 0) ? aB0 : (ks == 1) ? aB1 : (ks == 2) ? aB2 : aB3;
            const int cs = (ks * 4 + lq) ^ (lr & 7);
            #pragma unroll
            for (int nr = 0; nr < NT; ++nr) {
                bf16x8 bF = *reinterpret_cast<const bf16x8*>(&lB[(nr * 16 + lr) * KC + cs * 8]);
                acc[0][nr] = __builtin_amdgcn_mfma_f32_16x16x32_bf16(aF0, bF, acc[0][nr], 0, 0, 0);
                acc[1][nr] = __builtin_amdgcn_mfma_f32_16x16x32_bf16(aF1, bF, acc[1][nr], 0, 0, 0);
            }
        }
        if (kc + 1 < NKC) __syncthreads();
    }

    float alv[NT], arv[NT];
    #pragma unroll
    for (int nr = 0; nr < NT; ++nr) {
        int c = nr * 16 + lr;
        alv[nr] = (c < OUTW) ? al[c] : 0.f;
        arv[nr] = (c < OUTW) ? ar[c] : 0.f;
    }
    #pragma unroll
    for (int mr = 0; mr < 2; ++mr) {
        const int rb = (mr == 0) ? row0 : row1;
        #pragma unroll
        for (int reg = 0; reg < 4; ++reg) {
            int gr = rb + lq * 4 + reg;
            bool ok = gr < M;
            if (ok) {
                #pragma unroll
                for (int nr = 0; nr < NT; ++nr) {
                    int gc = nr * 16 + lr;
                    if (gc < OUTW) C[(size_t)gr * OUTW + gc] = f2b(acc[mr][nr][reg]);
                }
            }
            float pl[NH] = {}, pr[NH] = {};
            #pragma unroll
            for (int nr = 0; nr < NT; ++nr) {
                int hidx = (NH == 1) ? 0 : (nr >> 1);
                pl[hidx] = fmaf(acc[mr][nr][reg], alv[nr], pl[hidx]);
                pr[hidx] = fmaf(acc[mr][nr][reg], arv[nr], pr[hidx]);
            }
            #pragma unroll
            for (int o = 8; o >= 1; o >>= 1) {
                #pragma unroll
                for (int hh = 0; hh < NH; ++hh) {
                    pl[hh] += __shfl_xor(pl[hh], o);
                    pr[hh] += __shfl_xor(pr[hh], o);
                }
            }
            if (ok && lr == 0) {
                #pragma unroll
                for (int hh = 0; hh < NH; ++hh) {
                    el[gr * NH + hh] = pl[hh];
                    er[gr * NH + hh] = pr[hh];
                }
            }
        }
    }
}

// ============================== aggregation v6 (unchanged) ==============================

template<bool RELU>
__global__ __launch_bounds__(256) void agg4v6(const char* __restrict__ hbase,
                                              const float4* __restrict__ el4,
                                              const float4* __restrict__ er4,
                                              const float* __restrict__ bias,
                                              const int* __restrict__ rowptr,
                                              const int* __restrict__ csrc,
                                              u32* __restrict__ out, int N) {
    __shared__ u32 s_ed[BCAP][8];
    __shared__ int s_off[9];
    const int tid = threadIdx.x, w = tid >> 6, lane = tid & 63;
    const int base = blockIdx.x * 8;
    if (tid < 9) {
        int n = base + tid;
        s_off[tid] = rowptr[n <= N ? n : N];
    }
    __syncthreads();
    const int beg_blk = s_off[0];
    const int T = s_off[8] - beg_blk;
    const int hh = lane >> 4;
    const u32 lshl = (u32)(lane << 2);
    const float2 bv = reinterpret_cast<const float2*>(bias)[lane];
    const bool small = (T <= BCAP);

    if (small) {
        for (int t = tid; t < T; t += 256) {
            int sid = csrc[beg_blk + t];
            int nd = 0;
            #pragma unroll
            for (int k = 1; k < 8; ++k) nd += (t >= (s_off[k] - beg_blk)) ? 1 : 0;
            float4 er = er4[base + nd];
            float4 ev = el4[sid];
            float e0 = ev.x + er.x; e0 = e0 > 0.f ? e0 : 0.2f * e0;
            float e1 = ev.y + er.y; e1 = e1 > 0.f ? e1 : 0.2f * e1;
            float e2 = ev.z + er.z; e2 = e2 > 0.f ? e2 : 0.2f * e2;
            float e3 = ev.w + er.w; e3 = e3 > 0.f ? e3 : 0.2f * e3;
            u32 so = (u32)sid << 8;
            *reinterpret_cast<int2*>(&s_ed[t][0]) = make_int2(__float_as_int(__expf(e0)), (int)so);
            *reinterpret_cast<int2*>(&s_ed[t][2]) = make_int2(__float_as_int(__expf(e1)), (int)so);
            *reinterpret_cast<int2*>(&s_ed[t][4]) = make_int2(__float_as_int(__expf(e2)), (int)so);
            *reinterpret_cast<int2*>(&s_ed[t][6]) = make_int2(__float_as_int(__expf(e3)), (int)so);
        }
    }
    __syncthreads();

    const int nA = base + 2 * w;
    if (nA >= N) return;
    const int nB = nA + 1;
    float aA[4] = {}, bA[4] = {}, sA[4] = {};
    float aB[4] = {}, bB[4] = {}, sB[4] = {};

    if (small) {
        const int oA0 = s_off[2 * w] - beg_blk, oA1 = s_off[2 * w + 1] - beg_blk;
        const int oB0 = oA1, oB1 = s_off[2 * w + 2] - beg_blk;
        const int dA = oA1 - oA0, dB = oB1 - oB0;
        const int it = max((dA + 3) >> 2, (dB + 3) >> 2);
        for (int i = 0; i < it; ++i) {
            const int pA = oA0 + i * 4, pB = oB0 + i * 4;
            #pragma unroll
            for (int k = 0; k < 4; ++k) {
                int j = pA + k; bool v = j < oA1;
                int2 rv = *reinterpret_cast<const int2*>(&s_ed[v ? j : 0][hh * 2]);
                float wg = v ? __int_as_float(rv.x) : 0.f;
                u32 hv = *reinterpret_cast<const u32*>(hbase + ((u32)rv.y | lshl));
                aA[k] = fmaf(wg, bflo(hv), aA[k]);
                bA[k] = fmaf(wg, bfhi(hv), bA[k]);
                sA[k] += wg;
            }
            #pragma unroll
            for (int k = 0; k < 4; ++k) {
                int j = pB + k; bool v = j < oB1;
                int2 rv = *reinterpret_cast<const int2*>(&s_ed[v ? j : 0][hh * 2]);
                float wg = v ? __int_as_float(rv.x) : 0.f;
                u32 hv = *reinterpret_cast<const u32*>(hbase + ((u32)rv.y | lshl));
                aB[k] = fmaf(wg, bflo(hv), aB[k]);
                bB[k] = fmaf(wg, bfhi(hv), bB[k]);
                sB[k] += wg;
            }
        }
        {
            float accA = (aA[0] + aA[1]) + (aA[2] + aA[3]);
            float accB = (bA[0] + bA[1]) + (bA[2] + bA[3]);
            float s = (sA[0] + sA[1]) + (sA[2] + sA[3]);
            float invs = (dA > 0) ? 1.f / s : 0.f;
            float oA = accA * invs + bv.x;
            float oB = accB * invs + bv.y;
            if (RELU) { oA = fmaxf(oA, 0.f); oB = fmaxf(oB, 0.f); }
            out[(size_t)nA * 64 + lane] = ((u32)f2b(oB) << 16) | (u32)f2b(oA);
        }
        {
            float accA = (aB[0] + aB[1]) + (aB[2] + aB[3]);
            float accB = (bB[0] + bB[1]) + (bB[2] + bB[3]);
            float s = (sB[0] + sB[1]) + (sB[2] + sB[3]);
            float invs = (dB > 0) ? 1.f / s : 0.f;
            float oA = accA * invs + bv.x;
            float oB = accB * invs + bv.y;
            if (RELU) { oA = fmaxf(oA, 0.f); oB = fmaxf(oB, 0.f); }
            if (nB < N)
                out[(size_t)nB * 64 + lane] = ((u32)f2b(oB) << 16) | (u32)f2b(oA);
        }
    } else {
        #pragma unroll
        for (int which = 0; which < 2; ++which) {
            int nd = nA + which;
            if (nd >= N) break;
            int beg = s_off[2 * w + which], end = s_off[2 * w + which + 1];
            float4 er = er4[nd];
            float er_h = hh == 0 ? er.x : hh == 1 ? er.y : hh == 2 ? er.z : er.w;
            float s = 0.f, accA = 0.f, accB = 0.f;
            for (int q = beg; q < end; ++q) {
                int sid = csrc[q];
                float4 ev = el4[sid];
                float e = (hh == 0 ? ev.x : hh == 1 ? ev.y : hh == 2 ? ev.z : ev.w) + er_h;
                e = e > 0.f ? e : 0.2f * e;
                float pe = __expf(e);
                u32 hv = *reinterpret_cast<const u32*>(hbase + (((u32)sid << 8) | lshl));
                s += pe;
                accA = fmaf(pe, bflo(hv), accA);
                accB = fmaf(pe, bfhi(hv), accB);
            }
            float invs = (end > beg) ? 1.f / s : 0.f;
            float oA = accA * invs + bv.x;
            float oB = accB * invs + bv.y;
            if (RELU) { oA = fmaxf(oA, 0.f); oB = fmaxf(oB, 0.f); }
            out[(size_t)nd * 64 + lane] = ((u32)f2b(oB) << 16) | (u32)f2b(oA);
        }
    }
}

// single head + bias + log_softmax(40); h3 [N,40] bf16
__global__ __launch_bounds__(256) void agg1v6(const char* __restrict__ hbase,
                                              const float* __restrict__ el,
                                              const float* __restrict__ er,
                                              const float* __restrict__ bias,
                                              const int* __restrict__ rowptr,
                                              const int* __restrict__ csrc,
                                              float* __restrict__ out, int N) {
    __shared__ u32 s_e1[BCAP][2];
    __shared__ int s_off[9];
    const int tid = threadIdx.x, w = tid >> 6, lane = tid & 63;
    const int base = blockIdx.x * 8;
    if (tid < 9) {
        int n = base + tid;
        s_off[tid] = rowptr[n <= N ? n : N];
    }
    __syncthreads();
    const int beg_blk = s_off[0];
    const int T = s_off[8] - beg_blk;
    const int ll = lane < 40 ? lane : 39;
    const u32 lloff = (u32)(ll << 1);
    const float bvv = (lane < 40) ? bias[lane] : 0.f;
    const bool small = (T <= BCAP);

    if (small) {
        for (int t = tid; t < T; t += 256) {
            int sid = csrc[beg_blk + t];
            int nd = 0;
            #pragma unroll
            for (int k = 1; k < 8; ++k) nd += (t >= (s_off[k] - beg_blk)) ? 1 : 0;
            float e = el[sid] + er[base + nd];
            e = e > 0.f ? e : 0.2f * e;
            *reinterpret_cast<int2*>(&s_e1[t][0]) =
                make_int2(__float_as_int(__expf(e)), (int)((u32)sid * 80u));
        }
    }
    __syncthreads();

    const int nA = base + 2 * w;
    if (nA >= N) return;
    const int nB = nA + 1;
    float aA[4] = {}, sA[4] = {}, aB[4] = {}, sB[4] = {};
    float accA, invsA, accB, invsB;
    bool haveB = (nB < N);

    if (small) {
        const int oA0 = s_off[2 * w] - beg_blk, oA1 = s_off[2 * w + 1] - beg_blk;
        const int oB0 = oA1, oB1 = s_off[2 * w + 2] - beg_blk;
        const int dA = oA1 - oA0, dB = oB1 - oB0;
        const int it = max((dA + 3) >> 2, (dB + 3) >> 2);
        for (int i = 0; i < it; ++i) {
            const int pA = oA0 + i * 4, pB = oB0 + i * 4;
            #pragma unroll
            for (int k = 0; k < 4; ++k) {
                int j = pA + k; bool v = j < oA1;
                int2 rv = *reinterpret_cast<const int2*>(&s_e1[v ? j : 0][0]);
                float wg = v ? __int_as_float(rv.x) : 0.f;
                u16 hv = *reinterpret_cast<const u16*>(hbase + ((u32)rv.y + lloff));
                aA[k] = fmaf(wg, b2f(hv), aA[k]);
                sA[k] += wg;
            }
            #pragma unroll
            for (int k = 0; k < 4; ++k) {
                int j = pB + k; bool v = j < oB1;
                int2 rv = *reinterpret_cast<const int2*>(&s_e1[v ? j : 0][0]);
                float wg = v ? __int_as_float(rv.x) : 0.f;
                u16 hv = *reinterpret_cast<const u16*>(hbase + ((u32)rv.y + lloff));
                aB[k] = fmaf(wg, b2f(hv), aB[k]);
                sB[k] += wg;
            }
        }
        accA = (aA[0] + aA[1]) + (aA[2] + aA[3]);
        float ssA = (sA[0] + sA[1]) + (sA[2] + sA[3]);
        invsA = (dA > 0) ? 1.f / ssA : 0.f;
        accB = (aB[0] + aB[1]) + (aB[2] + aB[3]);
        float ssB = (sB[0] + sB[1]) + (sB[2] + sB[3]);
        invsB = (dB > 0) ? 1.f / ssB : 0.f;
    } else {
        accA = 0.f; accB = 0.f; invsA = 0.f; invsB = 0.f;
        #pragma unroll
        for (int which = 0; which < 2; ++which) {
            int nd = nA + which;
            if (nd >= N) break;
            int beg = s_off[2 * w + which], end = s_off[2 * w + which + 1];
            float ern = er[nd];
            float s = 0.f, acc = 0.f;
            for (int q = beg; q < end; ++q) {
                int sid = csrc[q];
                float e = el[sid] + ern; e = e > 0.f ? e : 0.2f * e;
                float pe = __expf(e);
                u16 hv = *reinterpret_cast<const u16*>(hbase + ((u32)sid * 80u + lloff));
                s += pe;
                acc = fmaf(pe, b2f(hv), acc);
            }
            float inv = (end > beg) ? 1.f / s : 0.f;
            if (which == 0) { accA = acc; invsA = inv; }
            else { accB = acc; invsB = inv; }
        }
    }
    {
        float v = accA * invsA + bvv;
        float vv = (lane < 40) ? v : -INFINITY;
        float mx = vv;
        #pragma unroll
        for (int o = 32; o >= 1; o >>= 1) mx = fmaxf(mx, __shfl_xor(mx, o));
        float ex = (lane < 40) ? __expf(v - mx) : 0.f;
        float se = ex;
        #pragma unroll
        for (int o = 32; o >= 1; o >>= 1) se += __shfl_xor(se, o);
        if (lane < 40) out[(size_t)nA * 40 + lane] = v - mx - logf(se);
    }
    if (haveB) {
        float v = accB * invsB + bvv;
        float vv = (lane < 40) ? v : -INFINITY;
        float mx = vv;
        #pragma unroll
        for (int o = 32; o >= 1; o >>= 1) mx = fmaxf(mx, __shfl_xor(mx, o));
        float ex = (lane < 40) ? __expf(v - mx) : 0.f;
        float se = ex;
        #pragma unroll
        for (int o = 32; o >= 1; o >>= 1) se += __shfl_xor(se, o);
        if (lane < 40) out[(size_t)nB * 40 + lane] = v - mx - logf(se);
    }
}

// ============================== launch ==============================

extern "C" void kernel_launch(void* const* d_in, const int* in_sizes, int n_in,
                              void* d_out, int out_size, void* d_ws, size_t ws_size,
                              hipStream_t stream) {
    const float* feat = (const float*)d_in[0];
    const float* W1  = (const float*)d_in[1];
    const float* al1 = (const float*)d_in[2];
    const float* ar1 = (const float*)d_in[3];
    const float* b1  = (const float*)d_in[4];
    const float* W2  = (const float*)d_in[5];
    const float* al2 = (const float*)d_in[6];
    const float* ar2 = (const float*)d_in[7];
    const float* b2  = (const float*)d_in[8];
    const float* W3  = (const float*)d_in[9];
    const float* al3 = (const float*)d_in[10];
    const float* ar3 = (const float*)d_in[11];
    const float* b3  = (const float*)d_in[12];
    const int*   src = (const int*)d_in[13];
    const int*   dst = (const int*)d_in[14];
    float* out = (float*)d_out;
    const int N = NN, E = NE;

    char* ws = (char*)d_ws;
    size_t off = 0;
    auto alloc = [&](size_t bytes) -> char* {
        char* p = ws + off;
        off += (bytes + 255) & ~(size_t)255;
        return p;
    };
    int* bcnt   = (int*)alloc(256 * 4);
    int* bbase  = (int*)alloc(256 * 4);
    int* gcur   = (int*)alloc(256 * 4);
    int* rowptr = (int*)alloc((size_t)(N + 1) * 4);
    int* csrc   = (int*)alloc((size_t)E * 4);
    long long* ebuf = (long long*)alloc((size_t)E * 8);
    float* el   = (float*)alloc((size_t)N * 4 * 4);
    float* er   = (float*)alloc((size_t)N * 4 * 4);
    u16* hb     = (u16*)alloc((size_t)N * 128 * 2);
    u16* xb     = (u16*)alloc((size_t)N * 128 * 2);
    u16* h3     = (u16*)alloc((size_t)N * 40 * 2 + 256);
    u16* W1t    = (u16*)alloc((size_t)128 * 256 * 2);
    u16* W2t    = (u16*)alloc((size_t)128 * 128 * 2);
    u16* W3t    = (u16*)alloc((size_t)48 * 128 * 2);

    // ---- CSR build ----
    hipMemsetAsync(bcnt, 0, NBUC * 4, stream);
    bucket_cnt<<<1024, 256, 0, stream>>>(dst, bcnt, E);
    bucket_scan<<<1, 256, 0, stream>>>(bcnt, bbase, gcur);
    part1<<<P1B, 256, 0, stream>>>(src, dst, gcur, ebuf);
    part2B<<<NBUC, 256, 0, stream>>>(bbase, ebuf, rowptr, csrc);

    // ---- weight prep ----
    transW3<<<(32768 + 16384 + 6144 + 255) / 256, 256, 0, stream>>>(W1, W1t, W2, W2t, W3, W3t);

    int gemmGrid64 = (N + 63) / 64;
    int gemmGrid128 = (N + 127) / 128;
    int aggGrid = (N + 7) / 8;

    // ---- layer 1 (fp32 A, loads-first pipeline) ----
    gemm_s<256, 8, 128, true, 4><<<gemmGrid64, 256, 0, stream>>>(feat, W1t, al1, ar1, hb, el, er, N);
    agg4v6<true><<<aggGrid, 256, 0, stream>>>((const char*)hb, (const float4*)el, (const float4*)er,
                                              b1, rowptr, csrc, (u32*)xb, N);

    // ---- layer 2 (bf16 A, 2-tile, loads-first) ----
    gemm_s2<128, 8, 128, 4><<<gemmGrid128, 256, 0, stream>>>(xb, W2t, al2, ar2, hb, el, er, N);
    agg4v6<true><<<aggGrid, 256, 0, stream>>>((const char*)hb, (const float4*)el, (const float4*)er,
                                              b2, rowptr, csrc, (u32*)xb, N);

    // ---- layer 3 (bf16 A, 2-tile, + fused log_softmax) ----
    gemm_s2<128, 3, 40, 1><<<gemmGrid128, 256, 0, stream>>>(xb, W3t, al3, ar3, h3, el, er, N);
    agg1v6<<<aggGrid, 256, 0, stream>>>((const char*)h3, el, er, b3, rowptr, csrc, out, N);
}

// Round 16
// 264.686 us; speedup vs baseline: 1.0228x; 1.0228x over previous
//
#include <hip/hip_runtime.h>
#include <hip/hip_bf16.h>
#include <math.h>

#define NN 100000
#define NE 1000000
#define NPB 512                          // nodes per bucket (pow2, shift 9)
#define NBUC ((NN + NPB - 1) / NPB)      // 196
#define CAPB 8192                        // max staged edges per bucket
#define P1B 512                          // part1 blocks
#define P1E ((NE + P1B - 1) / P1B)       // 1954 edges per part1 block
#define BCAP 512                         // max edges per 8-node agg block

typedef __attribute__((ext_vector_type(8))) short bf16x8;
typedef __attribute__((ext_vector_type(4))) float f32x4;
typedef unsigned int u32;
typedef unsigned short u16;
typedef unsigned long long u64;

__device__ __forceinline__ u16 f2b(float f) {
    __hip_bfloat16 h = __float2bfloat16(f);
    return *reinterpret_cast<u16*>(&h);
}
__device__ __forceinline__ float b2f(u16 u) {
    __hip_bfloat16 h = *reinterpret_cast<__hip_bfloat16*>(&u);
    return __bfloat162float(h);
}
__device__ __forceinline__ float bflo(u32 v) { return __uint_as_float(v << 16); }
__device__ __forceinline__ float bfhi(u32 v) { return __uint_as_float(v & 0xffff0000u); }

// ============================== CSR: bucket count + scan ==============================

__global__ void bucket_cnt(const int* __restrict__ dst, int* __restrict__ bcnt, int E) {
    __shared__ int c[NBUC];
    for (int i = threadIdx.x; i < NBUC; i += 256) c[i] = 0;
    __syncthreads();
    int i = blockIdx.x * 256 + threadIdx.x;
    const int stride = gridDim.x * 256;
    for (; i < E; i += stride) atomicAdd(&c[dst[i] >> 9], 1);
    __syncthreads();
    for (int j = threadIdx.x; j < NBUC; j += 256)
        if (c[j]) atomicAdd(&bcnt[j], c[j]);
}

__global__ void bucket_scan(const int* __restrict__ bcnt, int* __restrict__ bbase,
                            int* __restrict__ gcur) {
    __shared__ int s[256];
    const int tid = threadIdx.x;
    int v = (tid < NBUC) ? bcnt[tid] : 0;
    s[tid] = v;
    __syncthreads();
    for (int off = 1; off < 256; off <<= 1) {
        int t = (tid >= off) ? s[tid - off] : 0;
        __syncthreads();
        s[tid] += t;
        __syncthreads();
    }
    if (tid < NBUC) {
        int excl = s[tid] - v;
        bbase[tid] = excl;
        gcur[tid] = excl;
    }
    if (tid == NBUC - 1) bbase[NBUC] = s[tid];
}

// ============================== CSR: bucketed edge partition ==============================

__global__ __launch_bounds__(256) void part1(const int* __restrict__ src,
                                             const int* __restrict__ dst,
                                             int* __restrict__ gcur,
                                             long long* __restrict__ ebuf) {
    __shared__ int cnt[256], sex[256], base[256], cur2[256], scn[256];
    __shared__ long long stage[P1E];
    const int tid = threadIdx.x;
    const int e0 = blockIdx.x * P1E;
    const int e1 = min(e0 + P1E, NE);
    cnt[tid] = 0;
    __syncthreads();
    for (int i = e0 + tid; i < e1; i += 256)
        atomicAdd(&cnt[dst[i] >> 9], 1);
    __syncthreads();
    int v = cnt[tid];
    scn[tid] = v;
    __syncthreads();
    #pragma unroll
    for (int off = 1; off < 256; off <<= 1) {
        int t = (tid >= off) ? scn[tid - off] : 0;
        __syncthreads();
        scn[tid] += t;
        __syncthreads();
    }
    sex[tid] = scn[tid] - v;
    if (tid < NBUC) base[tid] = (v > 0) ? atomicAdd(&gcur[tid], v) : 0;
    cur2[tid] = 0;
    __syncthreads();
    for (int i = e0 + tid; i < e1; i += 256) {
        int d = dst[i], s = src[i];
        int b = d >> 9;
        int slot = sex[b] + atomicAdd(&cur2[b], 1);
        stage[slot] = ((long long)(u32)d << 32) | (u32)s;
    }
    __syncthreads();
    const int tot = e1 - e0;
    for (int i = tid; i < tot; i += 256) {
        long long ll = stage[i];
        int b = (int)((u64)ll >> 32) >> 9;
        ebuf[(size_t)base[b] + (i - sex[b])] = ll;
    }
}

// per bucket: count per node, scan -> rowptr, scatter -> csrc (coalesced)
__global__ __launch_bounds__(256) void part2B(const int* __restrict__ bbase,
                                              const long long* __restrict__ ebuf,
                                              int* __restrict__ rowptr,
                                              int* __restrict__ csrc) {
    __shared__ int nb[NPB], cnt[NPB];
    __shared__ int stage[CAPB];
    __shared__ int ssum[256];
    const int tid = threadIdx.x;
    const int n0 = blockIdx.x << 9;
    const int nn = min(NPB, NN - n0);
    const int estart = bbase[blockIdx.x];
    const int eend = bbase[blockIdx.x + 1];
    const int tot = eend - estart;
    for (int i = tid; i < NPB; i += 256) cnt[i] = 0;
    __syncthreads();
    for (int i = estart + tid; i < eend; i += 256) {
        int ln = (int)((u64)ebuf[i] >> 32) - n0;
        atomicAdd(&cnt[ln], 1);
    }
    __syncthreads();
    int a = cnt[2 * tid], b = cnt[2 * tid + 1];
    int ts = a + b;
    ssum[tid] = ts;
    __syncthreads();
    #pragma unroll
    for (int off = 1; off < 256; off <<= 1) {
        int t = (tid >= off) ? ssum[tid - off] : 0;
        __syncthreads();
        ssum[tid] += t;
        __syncthreads();
    }
    int eb = ssum[tid] - ts;
    nb[2 * tid] = eb;
    nb[2 * tid + 1] = eb + a;
    if (2 * tid < nn)     rowptr[n0 + 2 * tid]     = estart + eb;
    if (2 * tid + 1 < nn) rowptr[n0 + 2 * tid + 1] = estart + eb + a;
    if (tid == 0 && blockIdx.x == gridDim.x - 1) rowptr[NN] = eend;
    __syncthreads();
    for (int i = tid; i < NPB; i += 256) cnt[i] = 0;
    __syncthreads();
    if (tot <= CAPB) {
        for (int i = estart + tid; i < eend; i += 256) {
            long long ll = ebuf[i];
            int ln = (int)((u64)ll >> 32) - n0;
            int pos = nb[ln] + atomicAdd(&cnt[ln], 1);
            stage[pos] = (int)ll;
        }
        __syncthreads();
        for (int i = tid; i < tot; i += 256) csrc[estart + i] = stage[i];
    } else {
        for (int i = estart + tid; i < eend; i += 256) {
            long long ll = ebuf[i];
            int ln = (int)((u64)ll >> 32) - n0;
            int pos = nb[ln] + atomicAdd(&cnt[ln], 1);
            csrc[estart + pos] = (int)ll;
        }
    }
}

// ============================== weight prep (+ fused wal/war columns) ==============================
// Wt layout (row-major [rows][K], bf16):
//  L1/L2: rows 0-127 = W^T; rows 128-131 = W·al per head; rows 132-135 = W·ar; rows 136-143 = 0.
//  L3:    rows 0-39 = W^T; row 40 = W·al; row 41 = W·ar; rows 42-47 = 0.
#define W1SZ (144 * 256)
#define W2SZ (144 * 128)
#define W3SZ (48 * 128)

__global__ void transW3(const float* __restrict__ W1, const float* __restrict__ al1,
                        const float* __restrict__ ar1, u16* __restrict__ W1t,
                        const float* __restrict__ W2, const float* __restrict__ al2,
                        const float* __restrict__ ar2, u16* __restrict__ W2t,
                        const float* __restrict__ W3, const float* __restrict__ al3,
                        const float* __restrict__ ar3, u16* __restrict__ W3t) {
    int idx = blockIdx.x * 256 + threadIdx.x;
    if (idx < W1SZ) {
        int n = idx / 256, k = idx % 256;
        float v = 0.f;
        if (n < 128) v = W1[(size_t)k * 128 + n];
        else if (n < 136) {
            int h = (n - 128) & 3;
            const float* a = (n < 132) ? al1 : ar1;
            float s = 0.f;
            #pragma unroll 8
            for (int f = 0; f < 32; ++f) s += W1[(size_t)k * 128 + h * 32 + f] * a[h * 32 + f];
            v = s;
        }
        W1t[idx] = f2b(v);
    } else if (idx < W1SZ + W2SZ) {
        int j = idx - W1SZ;
        int n = j / 128, k = j % 128;
        float v = 0.f;
        if (n < 128) v = W2[(size_t)k * 128 + n];
        else if (n < 136) {
            int h = (n - 128) & 3;
            const float* a = (n < 132) ? al2 : ar2;
            float s = 0.f;
            #pragma unroll 8
            for (int f = 0; f < 32; ++f) s += W2[(size_t)k * 128 + h * 32 + f] * a[h * 32 + f];
            v = s;
        }
        W2t[j] = f2b(v);
    } else if (idx < W1SZ + W2SZ + W3SZ) {
        int j = idx - W1SZ - W2SZ;
        int n = j / 128, k = j % 128;
        float v = 0.f;
        if (n < 40) v = W3[(size_t)k * 40 + n];
        else if (n == 40 || n == 41) {
            const float* a = (n == 40) ? al3 : ar3;
            float s = 0.f;
            #pragma unroll 8
            for (int f = 0; f < 40; ++f) s += W3[(size_t)k * 40 + f] * a[f];
            v = s;
        }
        W3t[j] = f2b(v);
    }
}

// ============================== MFMA GEMM v8: el/er as extra C columns ==============================
// C[M,OUTW](bf16) = A[M,K] * Wt[NT*16,K]^T; el/er read off columns [ELCOL, ELCOL+2*NH).
template<int K, int NT, int OUTW, bool AF32, int NH, int ELCOL>
__global__ __launch_bounds__(256, 2) void gemm_s(const void* __restrict__ Ap_,
                                                 const u16* __restrict__ Wt,
                                                 u16* __restrict__ C,
                                                 float* __restrict__ el,
                                                 float* __restrict__ er, int M) {
    constexpr int KC = 128;
    constexpr int NKC = K / KC;
    constexpr int NB = NT * 16;
    constexpr int CHK = KC / 8;
    __shared__ u16 lB[NB * KC];
    const int tid = threadIdx.x;
    const int w = tid >> 6, l = tid & 63;
    const int lr = l & 15, lq = l >> 4;
    const int row0 = blockIdx.x * 64 + w * 16;
    const u16* Ab = (const u16*)Ap_;
    const float* Af = (const float*)Ap_;

    int gr0 = row0 + lr; if (gr0 >= M) gr0 = M - 1;
    const size_t aoff = (size_t)gr0 * K;

    f32x4 acc[NT] = {};
    #pragma unroll
    for (int kc = 0; kc < NKC; ++kc) {
        // (1) issue A loads first
        float4 v0, v1, v2, v3, v4, v5, v6, v7;
        bf16x8 a0, a1, a2, a3;
        if (AF32) {
            const float* ap = &Af[aoff + kc * KC];
            v0 = *reinterpret_cast<const float4*>(ap + 0 * 32 + lq * 8);
            v1 = *reinterpret_cast<const float4*>(ap + 0 * 32 + lq * 8 + 4);
            v2 = *reinterpret_cast<const float4*>(ap + 1 * 32 + lq * 8);
            v3 = *reinterpret_cast<const float4*>(ap + 1 * 32 + lq * 8 + 4);
            v4 = *reinterpret_cast<const float4*>(ap + 2 * 32 + lq * 8);
            v5 = *reinterpret_cast<const float4*>(ap + 2 * 32 + lq * 8 + 4);
            v6 = *reinterpret_cast<const float4*>(ap + 3 * 32 + lq * 8);
            v7 = *reinterpret_cast<const float4*>(ap + 3 * 32 + lq * 8 + 4);
        } else {
            a0 = *reinterpret_cast<const bf16x8*>(&Ab[aoff + kc * KC + 0 * 32 + lq * 8]);
            a1 = *reinterpret_cast<const bf16x8*>(&Ab[aoff + kc * KC + 1 * 32 + lq * 8]);
            a2 = *reinterpret_cast<const bf16x8*>(&Ab[aoff + kc * KC + 2 * 32 + lq * 8]);
            a3 = *reinterpret_cast<const bf16x8*>(&Ab[aoff + kc * KC + 3 * 32 + lq * 8]);
        }
        // (2) stage B chunk
        for (int idx = tid; idx < NB * CHK; idx += 256) {
            int row = idx / CHK, c = idx % CHK;
            float4 v = *reinterpret_cast<const float4*>(&Wt[(size_t)row * K + kc * KC + c * 8]);
            int cs = c ^ (row & 7);
            *reinterpret_cast<float4*>(&lB[row * KC + cs * 8]) = v;
        }
        __syncthreads();
        // (3) convert (fp32 path)
        if (AF32) {
            a0[0] = (short)f2b(v0.x); a0[1] = (short)f2b(v0.y); a0[2] = (short)f2b(v0.z); a0[3] = (short)f2b(v0.w);
            a0[4] = (short)f2b(v1.x); a0[5] = (short)f2b(v1.y); a0[6] = (short)f2b(v1.z); a0[7] = (short)f2b(v1.w);
            a1[0] = (short)f2b(v2.x); a1[1] = (short)f2b(v2.y); a1[2] = (short)f2b(v2.z); a1[3] = (short)f2b(v2.w);
            a1[4] = (short)f2b(v3.x); a1[5] = (short)f2b(v3.y); a1[6] = (short)f2b(v3.z); a1[7] = (short)f2b(v3.w);
            a2[0] = (short)f2b(v4.x); a2[1] = (short)f2b(v4.y); a2[2] = (short)f2b(v4.z); a2[3] = (short)f2b(v4.w);
            a2[4] = (short)f2b(v5.x); a2[5] = (short)f2b(v5.y); a2[6] = (short)f2b(v5.z); a2[7] = (short)f2b(v5.w);
            a3[0] = (short)f2b(v6.x); a3[1] = (short)f2b(v6.y); a3[2] = (short)f2b(v6.z); a3[3] = (short)f2b(v6.w);
            a3[4] = (short)f2b(v7.x); a3[5] = (short)f2b(v7.y); a3[6] = (short)f2b(v7.z); a3[7] = (short)f2b(v7.w);
        }
        // (4) MFMA
        #pragma unroll
        for (int ks = 0; ks < 4; ++ks) {
            bf16x8 aF = (ks == 0) ? a0 : (ks == 1) ? a1 : (ks == 2) ? a2 : a3;
            const int cs = (ks * 4 + lq) ^ (lr & 7);
            #pragma unroll
            for (int nr = 0; nr < NT; ++nr) {
                bf16x8 bF = *reinterpret_cast<const bf16x8*>(&lB[(nr * 16 + lr) * KC + cs * 8]);
                acc[nr] = __builtin_amdgcn_mfma_f32_16x16x32_bf16(aF, bF, acc[nr], 0, 0, 0);
            }
        }
        if (kc + 1 < NKC) __syncthreads();
    }

    // epilogue: C store + el/er column extraction (C/D layout: col=lr, row=lq*4+reg [m89])
    #pragma unroll
    for (int reg = 0; reg < 4; ++reg) {
        int gr = row0 + lq * 4 + reg;
        if (gr < M) {
            #pragma unroll
            for (int nr = 0; nr < NT; ++nr) {
                int gc = nr * 16 + lr;
                float v = acc[nr][reg];
                if (gc < OUTW) C[(size_t)gr * OUTW + gc] = f2b(v);
                else if (gc >= ELCOL && gc < ELCOL + NH) el[gr * NH + (gc - ELCOL)] = v;
                else if (gc >= ELCOL + NH && gc < ELCOL + 2 * NH) er[gr * NH + (gc - ELCOL - NH)] = v;
            }
        }
    }
}

// 2 M-tiles/block variant (bf16 A)
template<int K, int NT, int OUTW, int NH, int ELCOL>
__global__ __launch_bounds__(256, 2) void gemm_s2(const u16* __restrict__ Ab,
                                                  const u16* __restrict__ Wt,
                                                  u16* __restrict__ C,
                                                  float* __restrict__ el,
                                                  float* __restrict__ er, int M) {
    constexpr int KC = 128;
    constexpr int NKC = K / KC;
    constexpr int NB = NT * 16;
    constexpr int CHK = KC / 8;
    __shared__ u16 lB[NB * KC];
    const int tid = threadIdx.x;
    const int w = tid >> 6, l = tid & 63;
    const int lr = l & 15, lq = l >> 4;
    const int row0 = blockIdx.x * 128 + w * 16;
    const int row1 = row0 + 64;

    int gr0 = row0 + lr; if (gr0 >= M) gr0 = M - 1;
    int gr1 = row1 + lr; if (gr1 >= M) gr1 = M - 1;
    const size_t aoff0 = (size_t)gr0 * K;
    const size_t aoff1 = (size_t)gr1 * K;

    f32x4 acc[2][NT] = {};
    #pragma unroll
    for (int kc = 0; kc < NKC; ++kc) {
        bf16x8 aA0 = *reinterpret_cast<const bf16x8*>(&Ab[aoff0 + kc * KC + 0 * 32 + lq * 8]);
        bf16x8 aA1 = *reinterpret_cast<const bf16x8*>(&Ab[aoff0 + kc * KC + 1 * 32 + lq * 8]);
        bf16x8 aA2 = *reinterpret_cast<const bf16x8*>(&Ab[aoff0 + kc * KC + 2 * 32 + lq * 8]);
        bf16x8 aA3 = *reinterpret_cast<const bf16x8*>(&Ab[aoff0 + kc * KC + 3 * 32 + lq * 8]);
        bf16x8 aB0 = *reinterpret_cast<const bf16x8*>(&Ab[aoff1 + kc * KC + 0 * 32 + lq * 8]);
        bf16x8 aB1 = *reinterpret_cast<const bf16x8*>(&Ab[aoff1 + kc * KC + 1 * 32 + lq * 8]);
        bf16x8 aB2 = *reinterpret_cast<const bf16x8*>(&Ab[aoff1 + kc * KC + 2 * 32 + lq * 8]);
        bf16x8 aB3 = *reinterpret_cast<const bf16x8*>(&Ab[aoff1 + kc * KC + 3 * 32 + lq * 8]);
        for (int idx = tid; idx < NB * CHK; idx += 256) {
            int row = idx / CHK, c = idx % CHK;
            float4 v = *reinterpret_cast<const float4*>(&Wt[(size_t)row * K + kc * KC + c * 8]);
            int cs = c ^ (row & 7);
            *reinterpret_cast<float4*>(&lB[row * KC + cs * 8]) = v;
        }
        __syncthreads();
        #pragma unroll
        for (int ks = 0; ks < 4; ++ks) {
            bf16x8 aF0 = (ks == 0) ? aA0 : (ks == 1) ? aA1 : (ks == 2) ? aA2 : aA3;
            bf16x8 aF1 = (ks == 0) ? aB0 : (ks == 1) ? aB1 : (ks == 2) ? aB2 : aB3;
            const int cs = (ks * 4 + lq) ^ (lr & 7);
            #pragma unroll
            for (int nr = 0; nr < NT; ++nr) {
                bf16x8 bF = *reinterpret_cast<const bf16x8*>(&lB[(nr * 16 + lr) * KC + cs * 8]);
                acc[0][nr] = __builtin_amdgcn_mfma_f32_16x16x32_bf16(aF0, bF, acc[0][nr], 0, 0, 0);
                acc[1][nr] = __builtin_amdgcn_mfma_f32_16x16x32_bf16(aF1, bF, acc[1][nr], 0, 0, 0);
            }
        }
        if (kc + 1 < NKC) __syncthreads();
    }

    #pragma unroll
    for (int mr = 0; mr < 2; ++mr) {
        const int rb = (mr == 0) ? row0 : row1;
        #pragma unroll
        for (int reg = 0; reg < 4; ++reg) {
            int gr = rb + lq * 4 + reg;
            if (gr < M) {
                #pragma unroll
                for (int nr = 0; nr < NT; ++nr) {
                    int gc = nr * 16 + lr;
                    float v = acc[mr][nr][reg];
                    if (gc < OUTW) C[(size_t)gr * OUTW + gc] = f2b(v);
                    else if (gc >= ELCOL && gc < ELCOL + NH) el[gr * NH + (gc - ELCOL)] = v;
                    else if (gc >= ELCOL + NH && gc < ELCOL + 2 * NH) er[gr * NH + (gc - ELCOL - NH)] = v;
                }
            }
        }
    }
}

// ============================== aggregation v6 (unchanged) ==============================

template<bool RELU>
__global__ __launch_bounds__(256) void agg4v6(const char* __restrict__ hbase,
                                              const float4* __restrict__ el4,
                                              const float4* __restrict__ er4,
                                              const float* __restrict__ bias,
                                              const int* __restrict__ rowptr,
                                              const int* __restrict__ csrc,
                                              u32* __restrict__ out, int N) {
    __shared__ u32 s_ed[BCAP][8];
    __shared__ int s_off[9];
    const int tid = threadIdx.x, w = tid >> 6, lane = tid & 63;
    const int base = blockIdx.x * 8;
    if (tid < 9) {
        int n = base + tid;
        s_off[tid] = rowptr[n <= N ? n : N];
    }
    __syncthreads();
    const int beg_blk = s_off[0];
    const int T = s_off[8] - beg_blk;
    const int hh = lane >> 4;
    const u32 lshl = (u32)(lane << 2);
    const float2 bv = reinterpret_cast<const float2*>(bias)[lane];
    const bool small = (T <= BCAP);

    if (small) {
        for (int t = tid; t < T; t += 256) {
            int sid = csrc[beg_blk + t];
            int nd = 0;
            #pragma unroll
            for (int k = 1; k < 8; ++k) nd += (t >= (s_off[k] - beg_blk)) ? 1 : 0;
            float4 er = er4[base + nd];
            float4 ev = el4[sid];
            float e0 = ev.x + er.x; e0 = e0 > 0.f ? e0 : 0.2f * e0;
            float e1 = ev.y + er.y; e1 = e1 > 0.f ? e1 : 0.2f * e1;
            float e2 = ev.z + er.z; e2 = e2 > 0.f ? e2 : 0.2f * e2;
            float e3 = ev.w + er.w; e3 = e3 > 0.f ? e3 : 0.2f * e3;
            u32 so = (u32)sid << 8;
            *reinterpret_cast<int2*>(&s_ed[t][0]) = make_int2(__float_as_int(__expf(e0)), (int)so);
            *reinterpret_cast<int2*>(&s_ed[t][2]) = make_int2(__float_as_int(__expf(e1)), (int)so);
            *reinterpret_cast<int2*>(&s_ed[t][4]) = make_int2(__float_as_int(__expf(e2)), (int)so);
            *reinterpret_cast<int2*>(&s_ed[t][6]) = make_int2(__float_as_int(__expf(e3)), (int)so);
        }
    }
    __syncthreads();

    const int nA = base + 2 * w;
    if (nA >= N) return;
    const int nB = nA + 1;
    float aA[4] = {}, bA[4] = {}, sA[4] = {};
    float aB[4] = {}, bB[4] = {}, sB[4] = {};

    if (small) {
        const int oA0 = s_off[2 * w] - beg_blk, oA1 = s_off[2 * w + 1] - beg_blk;
        const int oB0 = oA1, oB1 = s_off[2 * w + 2] - beg_blk;
        const int dA = oA1 - oA0, dB = oB1 - oB0;
        const int it = max((dA + 3) >> 2, (dB + 3) >> 2);
        for (int i = 0; i < it; ++i) {
            const int pA = oA0 + i * 4, pB = oB0 + i * 4;
            #pragma unroll
            for (int k = 0; k < 4; ++k) {
                int j = pA + k; bool v = j < oA1;
                int2 rv = *reinterpret_cast<const int2*>(&s_ed[v ? j : 0][hh * 2]);
                float wg = v ? __int_as_float(rv.x) : 0.f;
                u32 hv = *reinterpret_cast<const u32*>(hbase + ((u32)rv.y | lshl));
                aA[k] = fmaf(wg, bflo(hv), aA[k]);
                bA[k] = fmaf(wg, bfhi(hv), bA[k]);
                sA[k] += wg;
            }
            #pragma unroll
            for (int k = 0; k < 4; ++k) {
                int j = pB + k; bool v = j < oB1;
                int2 rv = *reinterpret_cast<const int2*>(&s_ed[v ? j : 0][hh * 2]);
                float wg = v ? __int_as_float(rv.x) : 0.f;
                u32 hv = *reinterpret_cast<const u32*>(hbase + ((u32)rv.y | lshl));
                aB[k] = fmaf(wg, bflo(hv), aB[k]);
                bB[k] = fmaf(wg, bfhi(hv), bB[k]);
                sB[k] += wg;
            }
        }
        {
            float accA = (aA[0] + aA[1]) + (aA[2] + aA[3]);
            float accB = (bA[0] + bA[1]) + (bA[2] + bA[3]);
            float s = (sA[0] + sA[1]) + (sA[2] + sA[3]);
            float invs = (dA > 0) ? 1.f / s : 0.f;
            float oA = accA * invs + bv.x;
            float oB = accB * invs + bv.y;
            if (RELU) { oA = fmaxf(oA, 0.f); oB = fmaxf(oB, 0.f); }
            out[(size_t)nA * 64 + lane] = ((u32)f2b(oB) << 16) | (u32)f2b(oA);
        }
        {
            float accA = (aB[0] + aB[1]) + (aB[2] + aB[3]);
            float accB = (bB[0] + bB[1]) + (bB[2] + bB[3]);
            float s = (sB[0] + sB[1]) + (sB[2] + sB[3]);
            float invs = (dB > 0) ? 1.f / s : 0.f;
            float oA = accA * invs + bv.x;
            float oB = accB * invs + bv.y;
            if (RELU) { oA = fmaxf(oA, 0.f); oB = fmaxf(oB, 0.f); }
            if (nB < N)
                out[(size_t)nB * 64 + lane] = ((u32)f2b(oB) << 16) | (u32)f2b(oA);
        }
    } else {
        #pragma unroll
        for (int which = 0; which < 2; ++which) {
            int nd = nA + which;
            if (nd >= N) break;
            int beg = s_off[2 * w + which], end = s_off[2 * w + which + 1];
            float4 er = er4[nd];
            float er_h = hh == 0 ? er.x : hh == 1 ? er.y : hh == 2 ? er.z : er.w;
            float s = 0.f, accA = 0.f, accB = 0.f;
            for (int q = beg; q < end; ++q) {
                int sid = csrc[q];
                float4 ev = el4[sid];
                float e = (hh == 0 ? ev.x : hh == 1 ? ev.y : hh == 2 ? ev.z : ev.w) + er_h;
                e = e > 0.f ? e : 0.2f * e;
                float pe = __expf(e);
                u32 hv = *reinterpret_cast<const u32*>(hbase + (((u32)sid << 8) | lshl));
                s += pe;
                accA = fmaf(pe, bflo(hv), accA);
                accB = fmaf(pe, bfhi(hv), accB);
            }
            float invs = (end > beg) ? 1.f / s : 0.f;
            float oA = accA * invs + bv.x;
            float oB = accB * invs + bv.y;
            if (RELU) { oA = fmaxf(oA, 0.f); oB = fmaxf(oB, 0.f); }
            out[(size_t)nd * 64 + lane] = ((u32)f2b(oB) << 16) | (u32)f2b(oA);
        }
    }
}

// single head + bias + log_softmax(40); h3 [N,40] bf16
__global__ __launch_bounds__(256) void agg1v6(const char* __restrict__ hbase,
                                              const float* __restrict__ el,
                                              const float* __restrict__ er,
                                              const float* __restrict__ bias,
                                              const int* __restrict__ rowptr,
                                              const int* __restrict__ csrc,
                                              float* __restrict__ out, int N) {
    __shared__ u32 s_e1[BCAP][2];
    __shared__ int s_off[9];
    const int tid = threadIdx.x, w = tid >> 6, lane = tid & 63;
    const int base = blockIdx.x * 8;
    if (tid < 9) {
        int n = base + tid;
        s_off[tid] = rowptr[n <= N ? n : N];
    }
    __syncthreads();
    const int beg_blk = s_off[0];
    const int T = s_off[8] - beg_blk;
    const int ll = lane < 40 ? lane : 39;
    const u32 lloff = (u32)(ll << 1);
    const float bvv = (lane < 40) ? bias[lane] : 0.f;
    const bool small = (T <= BCAP);

    if (small) {
        for (int t = tid; t < T; t += 256) {
            int sid = csrc[beg_blk + t];
            int nd = 0;
            #pragma unroll
            for (int k = 1; k < 8; ++k) nd += (t >= (s_off[k] - beg_blk)) ? 1 : 0;
            float e = el[sid] + er[base + nd];
            e = e > 0.f ? e : 0.2f * e;
            *reinterpret_cast<int2*>(&s_e1[t][0]) =
                make_int2(__float_as_int(__expf(e)), (int)((u32)sid * 80u));
        }
    }
    __syncthreads();

    const int nA = base + 2 * w;
    if (nA >= N) return;
    const int nB = nA + 1;
    float aA[4] = {}, sA[4] = {}, aB[4] = {}, sB[4] = {};
    float accA, invsA, accB, invsB;
    bool haveB = (nB < N);

    if (small) {
        const int oA0 = s_off[2 * w] - beg_blk, oA1 = s_off[2 * w + 1] - beg_blk;
        const int oB0 = oA1, oB1 = s_off[2 * w + 2] - beg_blk;
        const int dA = oA1 - oA0, dB = oB1 - oB0;
        const int it = max((dA + 3) >> 2, (dB + 3) >> 2);
        for (int i = 0; i < it; ++i) {
            const int pA = oA0 + i * 4, pB = oB0 + i * 4;
            #pragma unroll
            for (int k = 0; k < 4; ++k) {
                int j = pA + k; bool v = j < oA1;
                int2 rv = *reinterpret_cast<const int2*>(&s_e1[v ? j : 0][0]);
                float wg = v ? __int_as_float(rv.x) : 0.f;
                u16 hv = *reinterpret_cast<const u16*>(hbase + ((u32)rv.y + lloff));
                aA[k] = fmaf(wg, b2f(hv), aA[k]);
                sA[k] += wg;
            }
            #pragma unroll
            for (int k = 0; k < 4; ++k) {
                int j = pB + k; bool v = j < oB1;
                int2 rv = *reinterpret_cast<const int2*>(&s_e1[v ? j : 0][0]);
                float wg = v ? __int_as_float(rv.x) : 0.f;
                u16 hv = *reinterpret_cast<const u16*>(hbase + ((u32)rv.y + lloff));
                aB[k] = fmaf(wg, b2f(hv), aB[k]);
                sB[k] += wg;
            }
        }
        accA = (aA[0] + aA[1]) + (aA[2] + aA[3]);
        float ssA = (sA[0] + sA[1]) + (sA[2] + sA[3]);
        invsA = (dA > 0) ? 1.f / ssA : 0.f;
        accB = (aB[0] + aB[1]) + (aB[2] + aB[3]);
        float ssB = (sB[0] + sB[1]) + (sB[2] + sB[3]);
        invsB = (dB > 0) ? 1.f / ssB : 0.f;
    } else {
        accA = 0.f; accB = 0.f; invsA = 0.f; invsB = 0.f;
        #pragma unroll
        for (int which = 0; which < 2; ++which) {
            int nd = nA + which;
            if (nd >= N) break;
            int beg = s_off[2 * w + which], end = s_off[2 * w + which + 1];
            float ern = er[nd];
            float s = 0.f, acc = 0.f;
            for (int q = beg; q < end; ++q) {
                int sid = csrc[q];
                float e = el[sid] + ern; e = e > 0.f ? e : 0.2f * e;
                float pe = __expf(e);
                u16 hv = *reinterpret_cast<const u16*>(hbase + ((u32)sid * 80u + lloff));
                s += pe;
                acc = fmaf(pe, b2f(hv), acc);
            }
            float inv = (end > beg) ? 1.f / s : 0.f;
            if (which == 0) { accA = acc; invsA = inv; }
            else { accB = acc; invsB = inv; }
        }
    }
    {
        float v = accA * invsA + bvv;
        float vv = (lane < 40) ? v : -INFINITY;
        float mx = vv;
        #pragma unroll
        for (int o = 32; o >= 1; o >>= 1) mx = fmaxf(mx, __shfl_xor(mx, o));
        float ex = (lane < 40) ? __expf(v - mx) : 0.f;
        float se = ex;
        #pragma unroll
        for (int o = 32; o >= 1; o >>= 1) se += __shfl_xor(se, o);
        if (lane < 40) out[(size_t)nA * 40 + lane] = v - mx - logf(se);
    }
    if (haveB) {
        float v = accB * invsB + bvv;
        float vv = (lane < 40) ? v : -INFINITY;
        float mx = vv;
        #pragma unroll
        for (int o = 32; o >= 1; o >>= 1) mx = fmaxf(mx, __shfl_xor(mx, o));
        float ex = (lane < 40) ? __expf(v - mx) : 0.f;
        float se = ex;
        #pragma unroll
        for (int o = 32; o >= 1; o >>= 1) se += __shfl_xor(se, o);
        if (lane < 40) out[(size_t)nB * 40 + lane] = v - mx - logf(se);
    }
}

// ============================== launch ==============================

extern "C" void kernel_launch(void* const* d_in, const int* in_sizes, int n_in,
                              void* d_out, int out_size, void* d_ws, size_t ws_size,
                              hipStream_t stream) {
    const float* feat = (const float*)d_in[0];
    const float* W1  = (const float*)d_in[1];
    const float* al1 = (const float*)d_in[2];
    const float* ar1 = (const float*)d_in[3];
    const float* b1  = (const float*)d_in[4];
    const float* W2  = (const float*)d_in[5];
    const float* al2 = (const float*)d_in[6];
    const float* ar2 = (const float*)d_in[7];
    const float* b2  = (const float*)d_in[8];
    const float* W3  = (const float*)d_in[9];
    const float* al3 = (const float*)d_in[10];
    const float* ar3 = (const float*)d_in[11];
    const float* b3  = (const float*)d_in[12];
    const int*   src = (const int*)d_in[13];
    const int*   dst = (const int*)d_in[14];
    float* out = (float*)d_out;
    const int N = NN, E = NE;

    char* ws = (char*)d_ws;
    size_t off = 0;
    auto alloc = [&](size_t bytes) -> char* {
        char* p = ws + off;
        off += (bytes + 255) & ~(size_t)255;
        return p;
    };
    int* bcnt   = (int*)alloc(256 * 4);
    int* bbase  = (int*)alloc(256 * 4);
    int* gcur   = (int*)alloc(256 * 4);
    int* rowptr = (int*)alloc((size_t)(N + 1) * 4);
    int* csrc   = (int*)alloc((size_t)E * 4);
    long long* ebuf = (long long*)alloc((size_t)E * 8);
    float* el   = (float*)alloc((size_t)N * 4 * 4);
    float* er   = (float*)alloc((size_t)N * 4 * 4);
    u16* hb     = (u16*)alloc((size_t)N * 128 * 2);
    u16* xb     = (u16*)alloc((size_t)N * 128 * 2);
    u16* h3     = (u16*)alloc((size_t)N * 40 * 2 + 256);
    u16* W1t    = (u16*)alloc((size_t)W1SZ * 2);
    u16* W2t    = (u16*)alloc((size_t)W2SZ * 2);
    u16* W3t    = (u16*)alloc((size_t)W3SZ * 2);

    // ---- CSR build ----
    hipMemsetAsync(bcnt, 0, NBUC * 4, stream);
    bucket_cnt<<<1024, 256, 0, stream>>>(dst, bcnt, E);
    bucket_scan<<<1, 256, 0, stream>>>(bcnt, bbase, gcur);
    part1<<<P1B, 256, 0, stream>>>(src, dst, gcur, ebuf);
    part2B<<<NBUC, 256, 0, stream>>>(bbase, ebuf, rowptr, csrc);

    // ---- weight prep (W^T + fused wal/war columns) ----
    transW3<<<(W1SZ + W2SZ + W3SZ + 255) / 256, 256, 0, stream>>>(
        W1, al1, ar1, W1t, W2, al2, ar2, W2t, W3, al3, ar3, W3t);

    int gemmGrid64 = (N + 63) / 64;
    int gemmGrid128 = (N + 127) / 128;
    int aggGrid = (N + 7) / 8;

    // ---- layer 1 (fp32 A; el/er as C columns 128-135) ----
    gemm_s<256, 9, 128, true, 4, 128><<<gemmGrid64, 256, 0, stream>>>(feat, W1t, hb, el, er, N);
    agg4v6<true><<<aggGrid, 256, 0, stream>>>((const char*)hb, (const float4*)el, (const float4*)er,
                                              b1, rowptr, csrc, (u32*)xb, N);

    // ---- layer 2 (bf16 A, 2-tile; el/er cols 128-135) ----
    gemm_s2<128, 9, 128, 4, 128><<<gemmGrid128, 256, 0, stream>>>(xb, W2t, hb, el, er, N);
    agg4v6<true><<<aggGrid, 256, 0, stream>>>((const char*)hb, (const float4*)el, (const float4*)er,
                                              b2, rowptr, csrc, (u32*)xb, N);

    // ---- layer 3 (bf16 A, 2-tile; el/er cols 40-41; + fused log_softmax) ----
    gemm_s2<128, 3, 40, 1, 40><<<gemmGrid128, 256, 0, stream>>>(xb, W3t, h3, el, er, N);
    agg1v6<<<aggGrid, 256, 0, stream>>>((const char*)h3, el, er, b3, rowptr, csrc, out, N);
}